// Round 8
// baseline (43.382 us; speedup 1.0000x reference)
//
#include <hip/hip_runtime.h>
#include <math.h>

#define B_  8
#define L_  4096
#define C_  256
#define TL  32

// ---- DPP wave-sum on the VALU pipe (no LDS traffic) ----
// Mirror-based sequence (direction-proof). After wave_sum_hi, ALL of
// lanes 48..63 hold the full 64-lane sum.
template<int CTRL, int RM>
__device__ __forceinline__ float dpp_add(float v) {
    int mv = __builtin_amdgcn_update_dpp(0, __float_as_int(v), CTRL, RM, 0xf, true);
    return v + __int_as_float(mv);
}
__device__ __forceinline__ float wave_sum_hi(float v) {
    v = dpp_add<0xB1, 0xf>(v);   // quad_perm [1,0,3,2]  (xor 1)
    v = dpp_add<0x4E, 0xf>(v);   // quad_perm [2,3,0,1]  (xor 2)
    v = dpp_add<0x141, 0xf>(v);  // row_half_mirror      (8-lane allreduce)
    v = dpp_add<0x140, 0xf>(v);  // row_mirror           (16-lane allreduce)
    v = dpp_add<0x142, 0xa>(v);  // row_bcast15 -> rows 1,3
    v = dpp_add<0x143, 0xc>(v);  // row_bcast31 -> rows 2,3 (row 3 = total)
    return v;
}

__global__ __launch_bounds__(256, 4)
void dconv1d_kernel(const float* __restrict__ x,
                    const float* __restrict__ w_off,
                    const float* __restrict__ b_off,
                    const float* __restrict__ w_mask,
                    const float* __restrict__ b_mask,
                    float* __restrict__ out) {
    __shared__ float s_tile[TL * C_];       // 32 KB
    __shared__ float4 s_prm[3][TL];         // {wf, wc, fl*C (int bits), ce*C (int bits)}

    const int tid  = threadIdx.x;
    const int lane = tid & 63;
    const int g    = tid >> 6;          // wave 0..3
    const int l0   = blockIdx.x * TL;
    const int b    = blockIdx.y;
    const float* __restrict__ xb = x + (size_t)b * L_ * C_;

    // biases (wave-uniform scalars)
    const float bo0 = b_off[0],  bo1 = b_off[1],  bo2 = b_off[2];
    const float bm0 = b_mask[0], bm1 = b_mask[1], bm2 = b_mask[2];

    // weights in registers: lane owns channels lane*4 .. lane*4+3
    float w_r[6][12];
    #pragma unroll
    for (int o = 0; o < 6; ++o) {
        const float* ws = (o < 3) ? (w_off + o * (C_ * 3))
                                  : (w_mask + (o - 3) * (C_ * 3));
        const float4* wp = reinterpret_cast<const float4*>(ws + lane * 12);
        float4 q0 = wp[0], q1 = wp[1], q2 = wp[2];
        w_r[o][0]=q0.x; w_r[o][1] =q0.y; w_r[o][2] =q0.z; w_r[o][3] =q0.w;
        w_r[o][4]=q1.x; w_r[o][5] =q1.y; w_r[o][6] =q1.z; w_r[o][7] =q1.w;
        w_r[o][8]=q2.x; w_r[o][9] =q2.y; w_r[o][10]=q2.z; w_r[o][11]=q2.w;
    }

    // ---- phase 1: conv -> params; wave g owns ll = g*8..g*8+7, 2 batches of 4
    #pragma unroll
    for (int bt = 0; bt < 2; ++bt) {
        const int lb4 = l0 + g * 8 + bt * 4;   // batch's first position
        float acc[4][6];
        #pragma unroll
        for (int i = 0; i < 4; ++i)
            #pragma unroll
            for (int o = 0; o < 6; ++o) acc[i][o] = 0.f;

        // 6 rows cover positions lb4..lb4+3, taps -1..+1 (each row loaded once)
        #pragma unroll
        for (int rr = 0; rr < 6; ++rr) {
            const int row = lb4 - 1 + rr;
            if (row >= 0 && row < L_) {
                const float4 xv = *reinterpret_cast<const float4*>(
                    xb + (size_t)row * C_ + lane * 4);
                #pragma unroll
                for (int t = 0; t < 3; ++t) {
                    const int i = rr - t;          // compile-time per (rr,t)
                    if (i >= 0 && i < 4) {
                        #pragma unroll
                        for (int o = 0; o < 6; ++o)
                            acc[i][o] += xv.x * w_r[o][0 + t] + xv.y * w_r[o][3 + t]
                                       + xv.z * w_r[o][6 + t] + xv.w * w_r[o][9 + t];
                    }
                }
            }
        }

        // VALU-pipe reduction: 24 independent DPP chains, zero DS ops
        #pragma unroll
        for (int i = 0; i < 4; ++i)
            #pragma unroll
            for (int o = 0; o < 6; ++o)
                acc[i][o] = wave_sum_hi(acc[i][o]);

        // writer lanes 48..59: lane 48 + pi*4 + k  (k<3), all sums replicated
        if (lane >= 48) {
            const int idx = lane - 48;     // 0..15
            const int pi  = idx >> 2;      // position in batch
            const int k   = idx & 3;       // tap
            if (k < 3) {
                float so = 0.f, sm = 0.f;
                #pragma unroll
                for (int ii = 0; ii < 4; ++ii)
                    #pragma unroll
                    for (int kk = 0; kk < 3; ++kk)
                        if (((ii << 2) | kk) == idx) {
                            so = acc[ii][kk];
                            sm = acc[ii][kk + 3];
                        }
                const float bo = (k == 0) ? bo0 : ((k == 1) ? bo1 : bo2);
                const float bm = (k == 0) ? bm0 : ((k == 1) ? bm1 : bm2);
                const int ll = g * 8 + bt * 4 + pi;
                const int l  = l0 + ll;
                const float off = so + bo;
                const float pos = fminf(fmaxf((float)l + off, 0.0f), (float)(L_ - 1));
                const float flf = floorf(pos);
                const int   fl  = (int)flf;
                const int   ce  = min(fl + 1, L_ - 1);
                const float a   = pos - flf;
                const float m   = 1.0f / (1.0f + __expf(-(sm + bm)));
                float4 p;
                p.x = m * (1.0f - a);                    // weight for x[fl]
                p.y = m * a;                             // weight for x[ce]
                p.z = __int_as_float(fl * C_);           // pre-scaled row offset
                p.w = __int_as_float(ce * C_);
                s_prm[k][ll] = p;
            }
        }
    }
    __syncthreads();

    // ---- phase 2: gather + weighted sum; thread owns channel c = tid ----
    {
        const int c = tid;
        #pragma unroll 4
        for (int ll = 0; ll < TL; ++ll) {
            float v = 0.f;
            #pragma unroll
            for (int k = 0; k < 3; ++k) {
                const float4 p = s_prm[k][ll];           // one ds_read_b128
                const float xf = xb[__float_as_int(p.z) + c];
                const float xc = xb[__float_as_int(p.w) + c];
                v += p.x * xf + p.y * xc;
            }
            s_tile[ll * C_ + (c ^ ll)] = v;
        }
    }
    __syncthreads();

    // ---- phase 3: transpose write-out (full 128B lines along l) ----
    {
        const int lw = tid & 31;
        const int cg = tid >> 5;
        #pragma unroll 8
        for (int cc = 0; cc < 32; ++cc) {
            const int c = cg * 32 + cc;
            out[((size_t)b * C_ + c) * L_ + l0 + lw] = s_tile[lw * C_ + (c ^ lw)];
        }
    }
}

extern "C" void kernel_launch(void* const* d_in, const int* in_sizes, int n_in,
                              void* d_out, int out_size, void* d_ws, size_t ws_size,
                              hipStream_t stream) {
    const float* x      = (const float*)d_in[0];
    const float* w_off  = (const float*)d_in[1];
    const float* b_off  = (const float*)d_in[2];
    const float* w_mask = (const float*)d_in[3];
    const float* b_mask = (const float*)d_in[4];
    float* out = (float*)d_out;

    dim3 grid(L_ / TL, B_);
    dconv1d_kernel<<<grid, 256, 0, stream>>>(x, w_off, b_off, w_mask, b_mask, out);
}

// Round 9
// 34.738 us; speedup vs baseline: 1.2488x; 1.2488x over previous
//
#include <hip/hip_runtime.h>
#include <math.h>

#define B_  8
#define L_  4096
#define C_  256
#define TL  32

// ---- DPP wave-sum on the VALU pipe (no LDS traffic) ----
// Mirror-based sequence (direction-proof, empirically verified R7).
// After wave_sum_hi, lanes 48..63 hold the full 64-lane sum.
template<int CTRL, int RM>
__device__ __forceinline__ float dpp_add(float v) {
    int mv = __builtin_amdgcn_update_dpp(0, __float_as_int(v), CTRL, RM, 0xf, true);
    return v + __int_as_float(mv);
}
__device__ __forceinline__ float wave_sum_hi(float v) {
    v = dpp_add<0xB1, 0xf>(v);   // quad_perm xor1
    v = dpp_add<0x4E, 0xf>(v);   // quad_perm xor2
    v = dpp_add<0x141, 0xf>(v);  // row_half_mirror
    v = dpp_add<0x140, 0xf>(v);  // row_mirror
    v = dpp_add<0x142, 0xa>(v);  // row_bcast15 -> rows 1,3
    v = dpp_add<0x143, 0xc>(v);  // row_bcast31 -> rows 2,3
    return v;
}
// broadcast lane 63's value to all lanes via SGPR (scalar pipe, no DS)
__device__ __forceinline__ float bcast63(float v) {
    return __int_as_float(__builtin_amdgcn_readlane(__float_as_int(v), 63));
}

__global__ __launch_bounds__(256, 4)
void dconv1d_kernel(const float* __restrict__ x,
                    const float* __restrict__ w_off,
                    const float* __restrict__ b_off,
                    const float* __restrict__ w_mask,
                    const float* __restrict__ b_mask,
                    float* __restrict__ out) {
    __shared__ float s_tile[TL * C_];   // 32 KB; rows swizzled in 16B granules

    const int tid  = threadIdx.x;
    const int lane = tid & 63;
    const int g    = tid >> 6;          // wave 0..3
    const int l0   = blockIdx.x * TL;
    const int b    = blockIdx.y;
    const float* __restrict__ xb = x + (size_t)b * L_ * C_;

    const float bo0 = b_off[0],  bo1 = b_off[1],  bo2 = b_off[2];
    const float bm0 = b_mask[0], bm1 = b_mask[1], bm2 = b_mask[2];

    // weights in registers: lane owns channels lane*4 .. lane*4+3
    float w_r[6][12];
    #pragma unroll
    for (int o = 0; o < 6; ++o) {
        const float* ws = (o < 3) ? (w_off + o * (C_ * 3))
                                  : (w_mask + (o - 3) * (C_ * 3));
        const float4* wp = reinterpret_cast<const float4*>(ws + lane * 12);
        float4 q0 = wp[0], q1 = wp[1], q2 = wp[2];
        w_r[o][0]=q0.x; w_r[o][1] =q0.y; w_r[o][2] =q0.z; w_r[o][3] =q0.w;
        w_r[o][4]=q1.x; w_r[o][5] =q1.y; w_r[o][6] =q1.z; w_r[o][7] =q1.w;
        w_r[o][8]=q2.x; w_r[o][9] =q2.y; w_r[o][10]=q2.z; w_r[o][11]=q2.w;
    }

    // ---- phase 1: conv sums for this wave's 8 positions (2 batches of 4) ----
    float sums[8][6];                    // wave-uniform after bcast63 (SGPRs)
    #pragma unroll
    for (int bt = 0; bt < 2; ++bt) {
        const int lb4 = l0 + g * 8 + bt * 4;
        float acc[4][6];
        #pragma unroll
        for (int i = 0; i < 4; ++i)
            #pragma unroll
            for (int o = 0; o < 6; ++o) acc[i][o] = 0.f;

        #pragma unroll
        for (int rr = 0; rr < 6; ++rr) {
            const int row = lb4 - 1 + rr;
            if (row >= 0 && row < L_) {
                const float4 xv = *reinterpret_cast<const float4*>(
                    xb + (size_t)row * C_ + lane * 4);
                #pragma unroll
                for (int t = 0; t < 3; ++t) {
                    const int i = rr - t;          // compile-time per (rr,t)
                    if (i >= 0 && i < 4) {
                        #pragma unroll
                        for (int o = 0; o < 6; ++o)
                            acc[i][o] += xv.x * w_r[o][0 + t] + xv.y * w_r[o][3 + t]
                                       + xv.z * w_r[o][6 + t] + xv.w * w_r[o][9 + t];
                    }
                }
            }
        }
        // 24 independent DPP chains on the VALU pipe, then SGPR broadcast
        #pragma unroll
        for (int i = 0; i < 4; ++i)
            #pragma unroll
            for (int o = 0; o < 6; ++o)
                sums[bt * 4 + i][o] = bcast63(wave_sum_hi(acc[i][o]));
    }

    // ---- phase 2: wave-local sampling of its own 8 positions ----
    // lane owns channels c4..c4+3; all params wave-uniform (zero DS reads).
    {
        const int c4 = lane << 2;
        #pragma unroll
        for (int i = 0; i < 8; ++i) {
            const int ll = g * 8 + i;
            const int l  = l0 + ll;
            float4 v = make_float4(0.f, 0.f, 0.f, 0.f);
            #pragma unroll
            for (int k = 0; k < 3; ++k) {
                const float bo = (k == 0) ? bo0 : ((k == 1) ? bo1 : bo2);
                const float bm = (k == 0) ? bm0 : ((k == 1) ? bm1 : bm2);
                const float off = sums[i][k] + bo;
                const float pos = fminf(fmaxf((float)l + off, 0.0f), (float)(L_ - 1));
                const float flf = floorf(pos);
                const int   fl  = (int)flf;
                const int   ce  = min(fl + 1, L_ - 1);
                const float a   = pos - flf;
                const float m   = 1.0f / (1.0f + __expf(-(sums[i][k + 3] + bm)));
                const float wf  = m * (1.0f - a);
                const float wc  = m * a;
                const float4 xf = *reinterpret_cast<const float4*>(
                    xb + (size_t)fl * C_ + c4);
                const float4 xc = *reinterpret_cast<const float4*>(
                    xb + (size_t)ce * C_ + c4);
                v.x += wf * xf.x + wc * xc.x;
                v.y += wf * xf.y + wc * xc.y;
                v.z += wf * xf.z + wc * xc.z;
                v.w += wf * xf.w + wc * xc.w;
            }
            // store 16B granule `lane` of row ll at swizzled slot lane^(ll&15)
            const int gr = lane ^ (ll & 15);
            *reinterpret_cast<float4*>(&s_tile[ll * C_ + (gr << 2)]) = v;
        }
    }
    __syncthreads();

    // ---- phase 3: transpose write-out, full 128B lines along l ----
    // thread = (row lw, granule stream q0); granule q holds channels 4q..4q+3
    {
        const int lw = tid & 31;
        const int q0 = tid >> 5;           // 0..7
        #pragma unroll
        for (int s = 0; s < 8; ++s) {
            const int q  = q0 + (s << 3);  // 0..63
            const int gr = q ^ (lw & 15);
            const float4 v = *reinterpret_cast<const float4*>(
                &s_tile[lw * C_ + (gr << 2)]);
            const size_t ob = ((size_t)b * C_ + (q << 2)) * L_ + l0 + lw;
            out[ob]          = v.x;
            out[ob + L_]     = v.y;
            out[ob + 2 * L_] = v.z;
            out[ob + 3 * L_] = v.w;
        }
    }
}

extern "C" void kernel_launch(void* const* d_in, const int* in_sizes, int n_in,
                              void* d_out, int out_size, void* d_ws, size_t ws_size,
                              hipStream_t stream) {
    const float* x      = (const float*)d_in[0];
    const float* w_off  = (const float*)d_in[1];
    const float* b_off  = (const float*)d_in[2];
    const float* w_mask = (const float*)d_in[3];
    const float* b_mask = (const float*)d_in[4];
    float* out = (float*)d_out;

    dim3 grid(L_ / TL, B_);
    dconv1d_kernel<<<grid, 256, 0, stream>>>(x, w_off, b_off, w_mask, b_mask, out);
}